// Round 8
// baseline (178.925 us; speedup 1.0000x reference)
//
#include <hip/hip_runtime.h>
#include <math.h>

// Problem constants (fixed by the reference: B=4, N=4096, D=3)
constexpr int B_  = 4;
constexpr int N_  = 4096;
constexpr int NV  = N_ * 3;      // 12288 flattened residual elements per (batch,dir)
constexpr int QPT = 8;           // queries per thread in the NN kernel

// float <-> monotonic uint key (order-preserving bijection on finite floats)
__device__ inline unsigned f2k(float f) {
    unsigned b = __float_as_uint(f);
    return b ^ ((unsigned)((int)b >> 31) | 0x80000000u);
}
__device__ inline float k2f(unsigned k) {
    unsigned b = (k & 0x80000000u) ? (k ^ 0x80000000u) : ~k;
    return __uint_as_float(b);
}

// ---------------------------------------------------------------------------
// Kernel 1: partial NN over a candidate chunk, 8 queries per thread.
// grid = (NCCH cand chunks, 2 query chunks, 8 pairs), block = 256.
// LDS candidates prescaled {-2bx,-2by,-2bz,|b|^2} -> d2 in 3 FMAs.
// One ds_read_b128 per candidate feeds 8 query updates (LDS amortized 8x).
// Strict '<' keeps the FIRST minimal index (jnp.argmin tie-break).
// ---------------------------------------------------------------------------
template <int NCCH>
__global__ __launch_bounds__(256) void nn_partial_kernel(const float* __restrict__ x,
                                                         const float* __restrict__ y,
                                                         float2* __restrict__ part) {
    constexpr int CCH = N_ / NCCH;
    __shared__ float4 s2[CCH];
    const int pair = blockIdx.z;
    const int b    = pair >> 1;
    const int dir  = pair & 1;              // 0: S1=x,S2=y ; 1: S1=y,S2=x
    const float* S1 = (dir == 0 ? x : y) + b * NV;
    const float* S2 = (dir == 0 ? y : x) + b * NV;
    const int cbase = blockIdx.x * CCH;

    for (int j = threadIdx.x; j < CCH; j += 256) {
        float bx = S2[(cbase + j) * 3 + 0];
        float by = S2[(cbase + j) * 3 + 1];
        float bz = S2[(cbase + j) * 3 + 2];
        s2[j] = make_float4(-2.f * bx, -2.f * by, -2.f * bz,
                            bx * bx + by * by + bz * bz);
    }
    __syncthreads();

    // 8 contiguous queries per thread: 24 floats = 6 aligned float4 loads.
    const int q0 = blockIdx.y * 2048 + threadIdx.x * QPT;
    float ax[QPT], ay[QPT], az[QPT];
    {
        const float4* p4 = (const float4*)(S1 + q0 * 3);
        float4 v[6];
        #pragma unroll
        for (int i = 0; i < 6; ++i) v[i] = p4[i];
        const float* f = (const float*)v;
        #pragma unroll
        for (int k = 0; k < QPT; ++k) {
            ax[k] = f[k * 3 + 0]; ay[k] = f[k * 3 + 1]; az[k] = f[k * 3 + 2];
        }
    }

    float best[QPT]; int idx[QPT];
    #pragma unroll
    for (int k = 0; k < QPT; ++k) { best[k] = INFINITY; idx[k] = 0; }

    #pragma unroll 2
    for (int j = 0; j < CCH; ++j) {
        float4 c = s2[j];                   // uniform address broadcast
        const int jg = cbase + j;           // SGPR
        #pragma unroll
        for (int k = 0; k < QPT; ++k) {
            // d2 = |b|^2 - 2 a.b  (3 FMAs on prescaled candidate)
            float d2 = fmaf(ax[k], c.x, fmaf(ay[k], c.y, fmaf(az[k], c.z, c.w)));
            if (d2 < best[k]) idx[k] = jg;  // v_cmp + v_cndmask
            best[k] = fminf(d2, best[k]);   // v_min
        }
    }

    float2 o[QPT];
    #pragma unroll
    for (int k = 0; k < QPT; ++k) o[k] = make_float2(best[k], (float)idx[k]);
    float4* op = (float4*)(part + (size_t)(pair * NCCH + blockIdx.x) * N_ + q0);
    #pragma unroll
    for (int i = 0; i < QPT / 2; ++i) op[i] = ((const float4*)o)[i];
}

// ---------------------------------------------------------------------------
// Kernel 2 (FUSED TAIL): one block per (batch,dir) pair, 512 threads.
//   A: merge NCCH partials per query (ascending chunk order + strict '<' ==
//      global first-index argmin), gather residuals, store monotonic keys
//      to LDS (no global residual round-trip).
//   B: 4x 8-bit MSD radix-select for ALL FOUR quantile order-stats at once.
//      Pass 1 histogram is shared by all quantiles (4 wave-privatized
//      copies, plain atomics). Passes 2-4 keep 4 per-quantile hists; prefix
//      matches are ~48/pass so atomic traffic is negligible.
//   C: fused count(<=key0)/min(>key0) scan -> linear-interp quantiles
//      (positions in fp32, identical to jnp.quantile).
//   D: two-pass masked mean/std from LDS keys (k2f is exact inverse, so
//      float comparisons/sums match the reference path).
// ---------------------------------------------------------------------------
template <int NCCH>
__global__ __launch_bounds__(512) void fused_tail_kernel(const float* __restrict__ x,
                                                         const float* __restrict__ y,
                                                         const float2* __restrict__ part,
                                                         float* __restrict__ stats) {
    __shared__ unsigned keys[NV];           // 48 KB
    __shared__ int hist4[4][256];           // 4 KB
    __shared__ unsigned s_prefix[4];
    __shared__ int s_want[4];
    __shared__ int s_cnt[4];
    __shared__ unsigned s_mn[4];
    __shared__ float s_qv[4];
    __shared__ float red[32];
    __shared__ float sh[8];

    const int pair = blockIdx.x;
    const int tid  = threadIdx.x;
    const int lane = tid & 63;
    const int wid  = tid >> 6;              // 8 waves
    const int b    = pair >> 1;
    const int dir  = pair & 1;
    const float* S1 = (dir == 0 ? x : y) + b * NV;
    const float* S2 = (dir == 0 ? y : x) + b * NV;

    // ---- Phase A: merge + residual keys into LDS ----
    for (int step = 0; step < 8; ++step) {  // 8 * 512 = 4096 queries
        const int q = step * 512 + tid;
        float best = INFINITY; int bidx = 0;
        #pragma unroll
        for (int c = 0; c < NCCH; ++c) {
            float2 p = part[(size_t)(pair * NCCH + c) * N_ + q];
            if (p.x < best) { best = p.x; bidx = (int)p.y; }
        }
        float rx = S1[q * 3 + 0] - S2[bidx * 3 + 0];
        float ry = S1[q * 3 + 1] - S2[bidx * 3 + 1];
        float rz = S1[q * 3 + 2] - S2[bidx * 3 + 2];
        keys[q * 3 + 0] = f2k(rx);
        keys[q * 3 + 1] = f2k(ry);
        keys[q * 3 + 2] = f2k(rz);
    }
    if (tid < 4) {
        const float Qs[4] = {0.05f, 0.95f, 0.25f, 0.75f};
        s_prefix[tid] = 0u;
        s_want[tid]   = (int)floorf(Qs[tid] * (float)(NV - 1));
    }
    __syncthreads();

    // ---- Phase B: 4 radix passes ----
    #pragma unroll 1
    for (int pass = 0; pass < 4; ++pass) {
        const int shift = 24 - 8 * pass;
        ((int*)hist4)[tid]       = 0;       // 1024 ints, 512 threads x2
        ((int*)hist4)[tid + 512] = 0;
        __syncthreads();

        if (pass == 0) {
            // all quantiles share pass-1; 4 wave-privatized copies
            for (int i = tid; i < NV; i += 512)
                atomicAdd(&hist4[wid & 3][keys[i] >> 24], 1);
        } else {
            const unsigned pmask = 0xFFFFFFFFu << (32 - 8 * pass);
            const unsigned pf0 = s_prefix[0], pf1 = s_prefix[1];
            const unsigned pf2 = s_prefix[2], pf3 = s_prefix[3];
            for (int i = tid; i < NV; i += 512) {
                const unsigned k  = keys[i];
                const unsigned kp = k & pmask;
                const int bin = (int)((k >> shift) & 255u);
                if (kp == pf0) atomicAdd(&hist4[0][bin], 1);
                if (kp == pf1) atomicAdd(&hist4[1][bin], 1);
                if (kp == pf2) atomicAdd(&hist4[2][bin], 1);
                if (kp == pf3) atomicAdd(&hist4[3][bin], 1);
            }
        }
        __syncthreads();

        // selection: wave t (t<4) scans quantile t's histogram
        if (wid < 4) {
            int c0, c1, c2, c3;
            if (pass == 0) {
                c0 = hist4[0][lane*4+0] + hist4[1][lane*4+0] + hist4[2][lane*4+0] + hist4[3][lane*4+0];
                c1 = hist4[0][lane*4+1] + hist4[1][lane*4+1] + hist4[2][lane*4+1] + hist4[3][lane*4+1];
                c2 = hist4[0][lane*4+2] + hist4[1][lane*4+2] + hist4[2][lane*4+2] + hist4[3][lane*4+2];
                c3 = hist4[0][lane*4+3] + hist4[1][lane*4+3] + hist4[2][lane*4+3] + hist4[3][lane*4+3];
            } else {
                c0 = hist4[wid][lane*4+0]; c1 = hist4[wid][lane*4+1];
                c2 = hist4[wid][lane*4+2]; c3 = hist4[wid][lane*4+3];
            }
            const int want = s_want[wid];
            int s = c0 + c1 + c2 + c3;
            int pre = s;
            #pragma unroll
            for (int off = 1; off < 64; off <<= 1) {
                int u = __shfl_up(pre, off);
                if (lane >= off) pre += u;
            }
            const int excl = pre - s;
            const bool hit = (want >= excl) && (want < excl + s);
            unsigned long long m = __ballot(hit);   // per-wave ballot
            const int hl = (int)(__ffsll(m) - 1);
            if (lane == hl) {
                int w = want - excl;
                int sel;
                if      (w < c0)           { sel = lane * 4 + 0; }
                else if (w < c0 + c1)      { sel = lane * 4 + 1; w -= c0; }
                else if (w < c0 + c1 + c2) { sel = lane * 4 + 2; w -= c0 + c1; }
                else                       { sel = lane * 4 + 3; w -= c0 + c1 + c2; }
                s_prefix[wid] |= ((unsigned)sel) << shift;
                s_want[wid] = w;
            }
        }
        __syncthreads();
    }

    // ---- Phase C: count(<=key0) and min(>key0) for all 4 quantiles ----
    if (tid < 4) { s_cnt[tid] = 0; s_mn[tid] = 0xFFFFFFFFu; }
    __syncthreads();
    const unsigned k0v0 = s_prefix[0], k0v1 = s_prefix[1];
    const unsigned k0v2 = s_prefix[2], k0v3 = s_prefix[3];
    int cnt0 = 0, cnt1 = 0, cnt2 = 0, cnt3 = 0;
    unsigned mn0 = 0xFFFFFFFFu, mn1 = 0xFFFFFFFFu, mn2 = 0xFFFFFFFFu, mn3 = 0xFFFFFFFFu;
    for (int i = tid; i < NV; i += 512) {
        const unsigned k = keys[i];
        if (k <= k0v0) cnt0++; else if (k < mn0) mn0 = k;
        if (k <= k0v1) cnt1++; else if (k < mn1) mn1 = k;
        if (k <= k0v2) cnt2++; else if (k < mn2) mn2 = k;
        if (k <= k0v3) cnt3++; else if (k < mn3) mn3 = k;
    }
    #pragma unroll
    for (int off = 32; off > 0; off >>= 1) {
        cnt0 += __shfl_down(cnt0, off); cnt1 += __shfl_down(cnt1, off);
        cnt2 += __shfl_down(cnt2, off); cnt3 += __shfl_down(cnt3, off);
        unsigned u0 = __shfl_down(mn0, off); mn0 = u0 < mn0 ? u0 : mn0;
        unsigned u1 = __shfl_down(mn1, off); mn1 = u1 < mn1 ? u1 : mn1;
        unsigned u2 = __shfl_down(mn2, off); mn2 = u2 < mn2 ? u2 : mn2;
        unsigned u3 = __shfl_down(mn3, off); mn3 = u3 < mn3 ? u3 : mn3;
    }
    if (lane == 0) {
        atomicAdd(&s_cnt[0], cnt0); atomicMin(&s_mn[0], mn0);
        atomicAdd(&s_cnt[1], cnt1); atomicMin(&s_mn[1], mn1);
        atomicAdd(&s_cnt[2], cnt2); atomicMin(&s_mn[2], mn2);
        atomicAdd(&s_cnt[3], cnt3); atomicMin(&s_mn[3], mn3);
    }
    __syncthreads();
    if (tid < 4) {
        const float Qs[4] = {0.05f, 0.95f, 0.25f, 0.75f};
        const float pos = Qs[tid] * (float)(NV - 1);
        const int   k0  = (int)floorf(pos);
        const float fr  = pos - (float)k0;
        const float v0  = k2f(s_prefix[tid]);
        const float v1  = (s_cnt[tid] >= k0 + 2) ? v0 : k2f(s_mn[tid]);
        s_qv[tid] = v0 + fr * (v1 - v0);
    }
    __syncthreads();
    const float q0 = s_qv[0], q1 = s_qv[1], q2 = s_qv[2], q3 = s_qv[3];

    // ---- Phase D: masked two-pass mean/std from LDS keys ----
    float cb = 0.f, sb = 0.f, ce = 0.f, se = 0.f;
    for (int i = tid; i < NV; i += 512) {
        const float val = k2f(keys[i]);
        if ((val < q0) || (val > q1)) { cb += 1.f; sb += val; }
        if ((val > q2) && (val < q3)) { ce += 1.f; se += val; }
    }
    #pragma unroll
    for (int off = 32; off > 0; off >>= 1) {
        cb += __shfl_down(cb, off); sb += __shfl_down(sb, off);
        ce += __shfl_down(ce, off); se += __shfl_down(se, off);
    }
    if (lane == 0) {
        red[wid * 4 + 0] = cb; red[wid * 4 + 1] = sb;
        red[wid * 4 + 2] = ce; red[wid * 4 + 3] = se;
    }
    __syncthreads();
    if (tid == 0) {
        float tcb = 0.f, tsb = 0.f, tce = 0.f, tse = 0.f;
        for (int w = 0; w < 8; ++w) {
            tcb += red[w * 4 + 0]; tsb += red[w * 4 + 1];
            tce += red[w * 4 + 2]; tse += red[w * 4 + 3];
        }
        sh[0] = tsb / tcb;  sh[1] = tse / tce;   // means
        sh[2] = tcb;        sh[3] = tce;         // counts
    }
    __syncthreads();
    const float mean_b = sh[0], mean_e = sh[1];
    const float nb = sh[2], ne = sh[3];

    float vb = 0.f, ve = 0.f;
    for (int i = tid; i < NV; i += 512) {
        const float val = k2f(keys[i]);
        if ((val < q0) || (val > q1)) { float d = val - mean_b; vb += d * d; }
        if ((val > q2) && (val < q3)) { float d = val - mean_e; ve += d * d; }
    }
    #pragma unroll
    for (int off = 32; off > 0; off >>= 1) {
        vb += __shfl_down(vb, off);
        ve += __shfl_down(ve, off);
    }
    __syncthreads();
    if (lane == 0) { red[wid * 2 + 0] = vb; red[wid * 2 + 1] = ve; }
    __syncthreads();
    if (tid == 0) {
        float tvb = 0.f, tve = 0.f;
        for (int w = 0; w < 8; ++w) { tvb += red[w * 2 + 0]; tve += red[w * 2 + 1]; }
        stats[pair * 2 + 0] = sqrtf(tvb / (nb - 1.f));   // unbiased std, begin
        stats[pair * 2 + 1] = sqrtf(tve / (ne - 1.f));   // unbiased std, end
    }
}

// ---------------------------------------------------------------------------
// Kernel 3: per-batch max over directions, mean over batches.
// ---------------------------------------------------------------------------
__global__ void final_kernel(const float* __restrict__ stats, float* __restrict__ out) {
    if (threadIdx.x == 0 && blockIdx.x == 0) {
        float sb = 0.f, se = 0.f;
        for (int b = 0; b < B_; ++b) {
            float b1 = stats[(b * 2 + 0) * 2 + 0];
            float b2 = stats[(b * 2 + 1) * 2 + 0];
            float e1 = stats[(b * 2 + 0) * 2 + 1];
            float e2 = stats[(b * 2 + 1) * 2 + 1];
            sb += fmaxf(b1, b2);
            se += fmaxf(e1, e2);
        }
        out[0] = sb / (float)B_;
        out[1] = se / (float)B_;
    }
}

template <int NCCH>
static void run_pipeline(const float* x, const float* y, float2* part,
                         float* stats, float* out, hipStream_t stream) {
    nn_partial_kernel<NCCH><<<dim3(NCCH, 2, 8), 256, 0, stream>>>(x, y, part);
    fused_tail_kernel<NCCH><<<8, 512, 0, stream>>>(x, y, part, stats);
    final_kernel<<<1, 64, 0, stream>>>(stats, out);
}

extern "C" void kernel_launch(void* const* d_in, const int* in_sizes, int n_in,
                              void* d_out, int out_size, void* d_ws, size_t ws_size,
                              hipStream_t stream) {
    const float* x = (const float*)d_in[0];
    const float* y = (const float*)d_in[1];
    float* out = (float*)d_out;

    float2* part  = (float2*)d_ws;
    const size_t need32 = (size_t)8 * 32 * N_ * sizeof(float2) + 64 * sizeof(float);

    if (ws_size >= need32) {
        float* stats = (float*)(part + (size_t)8 * 32 * N_);
        run_pipeline<32>(x, y, part, stats, out, stream);
    } else {
        float* stats = (float*)(part + (size_t)8 * 4 * N_);
        run_pipeline<4>(x, y, part, stats, out, stream);
    }
}

// Round 9
// 93.153 us; speedup vs baseline: 1.9208x; 1.9208x over previous
//
#include <hip/hip_runtime.h>
#include <math.h>

// Problem constants (fixed by the reference: B=4, N=4096, D=3)
constexpr int B_   = 4;
constexpr int N_   = 4096;
constexpr int NV   = N_ * 3;     // 12288 flattened residual elements per (batch,dir)
constexpr int QPT  = 8;          // queries per thread in the NN kernel
constexpr int NCCH = 32;         // candidate chunks
constexpr int CCH  = N_ / NCCH;  // 128 candidates per chunk

// float <-> monotonic uint key (order-preserving bijection on finite floats)
__device__ inline unsigned f2k(float f) {
    unsigned b = __float_as_uint(f);
    return b ^ ((unsigned)((int)b >> 31) | 0x80000000u);
}
__device__ inline float k2f(unsigned k) {
    unsigned b = (k & 0x80000000u) ? (k ^ 0x80000000u) : ~k;
    return __uint_as_float(b);
}

// ---------------------------------------------------------------------------
// Kernel 0: init best[] to u64 max so atomicMin works.
// ---------------------------------------------------------------------------
__global__ __launch_bounds__(256) void init_best_kernel(unsigned long long* __restrict__ best) {
    best[blockIdx.x * 256 + threadIdx.x] = 0xFFFFFFFFFFFFFFFFull;
}

// ---------------------------------------------------------------------------
// Kernel 1: NN over a candidate chunk, 8 queries/thread, merged via global
// atomicMin on packed (f2k(d2) << 32 | idx).  Monotonic key + idx low bits
// == argmin with FIRST-index tie-break (jnp.argmin): smaller d2 wins, equal
// d2 -> smaller global index wins.
// grid = (NCCH, 2 query chunks, 8 pairs), block = 256.
// ---------------------------------------------------------------------------
__global__ __launch_bounds__(256) void nn_atomic_kernel(const float* __restrict__ x,
                                                        const float* __restrict__ y,
                                                        unsigned long long* __restrict__ best) {
    __shared__ float4 s2[CCH];
    const int pair = blockIdx.z;
    const int b    = pair >> 1;
    const int dir  = pair & 1;              // 0: S1=x,S2=y ; 1: S1=y,S2=x
    const float* S1 = (dir == 0 ? x : y) + b * NV;
    const float* S2 = (dir == 0 ? y : x) + b * NV;
    const int cbase = blockIdx.x * CCH;

    for (int j = threadIdx.x; j < CCH; j += 256) {
        float bx = S2[(cbase + j) * 3 + 0];
        float by = S2[(cbase + j) * 3 + 1];
        float bz = S2[(cbase + j) * 3 + 2];
        s2[j] = make_float4(-2.f * bx, -2.f * by, -2.f * bz,
                            bx * bx + by * by + bz * bz);
    }
    __syncthreads();

    // 8 contiguous queries per thread: 24 floats = 6 aligned float4 loads.
    const int q0 = blockIdx.y * 2048 + threadIdx.x * QPT;
    float ax[QPT], ay[QPT], az[QPT];
    {
        const float4* p4 = (const float4*)(S1 + q0 * 3);
        float4 v[6];
        #pragma unroll
        for (int i = 0; i < 6; ++i) v[i] = p4[i];
        const float* f = (const float*)v;
        #pragma unroll
        for (int k = 0; k < QPT; ++k) {
            ax[k] = f[k * 3 + 0]; ay[k] = f[k * 3 + 1]; az[k] = f[k * 3 + 2];
        }
    }

    float bd[QPT]; int idx[QPT];
    #pragma unroll
    for (int k = 0; k < QPT; ++k) { bd[k] = INFINITY; idx[k] = 0; }

    #pragma unroll 2
    for (int j = 0; j < CCH; ++j) {
        float4 c = s2[j];                   // uniform address broadcast
        const int jg = cbase + j;
        #pragma unroll
        for (int k = 0; k < QPT; ++k) {
            // d2 = |b|^2 - 2 a.b  (3 FMAs on prescaled candidate)
            float d2 = fmaf(ax[k], c.x, fmaf(ay[k], c.y, fmaf(az[k], c.z, c.w)));
            if (d2 < bd[k]) idx[k] = jg;    // strict '<': first minimal index
            bd[k] = fminf(d2, bd[k]);
        }
    }

    unsigned long long* bq = best + (size_t)pair * N_ + q0;
    #pragma unroll
    for (int k = 0; k < QPT; ++k) {
        unsigned long long pk = ((unsigned long long)f2k(bd[k]) << 32)
                              | (unsigned)idx[k];
        atomicMin(&bq[k], pk);              // fire-and-forget, no return use
    }
}

// ---------------------------------------------------------------------------
// Kernel 2 (FUSED TAIL): one block per (batch,dir) pair, 512 threads.
//   A: read merged best[] (8 coalesced u64/thread), gather residuals,
//      monotonic keys -> LDS.
//   B: 4x 8-bit MSD radix-select for all four quantile order-stats at once
//      (uint4-vectorized scans; pass-1 hist has 8 wave-private copies).
//   C: fused count(<=key0)/min(>key0) -> linear-interp quantiles
//      (positions in fp32, identical to jnp.quantile).
//   D: two-pass masked mean/std from LDS keys (k2f exact inverse).
// ---------------------------------------------------------------------------
__global__ __launch_bounds__(512) void fused_tail_kernel(const float* __restrict__ x,
                                                         const float* __restrict__ y,
                                                         const unsigned long long* __restrict__ best,
                                                         float* __restrict__ stats) {
    __shared__ unsigned keys[NV];           // 48 KB
    __shared__ int hist8[8][256];           // 8 KB
    __shared__ unsigned s_prefix[4];
    __shared__ int s_want[4];
    __shared__ int s_cnt[4];
    __shared__ unsigned s_mn[4];
    __shared__ float s_qv[4];
    __shared__ float red[32];
    __shared__ float sh[8];

    const int pair = blockIdx.x;
    const int tid  = threadIdx.x;
    const int lane = tid & 63;
    const int wid  = tid >> 6;              // 8 waves
    const int b    = pair >> 1;
    const int dir  = pair & 1;
    const float* S1 = (dir == 0 ? x : y) + b * NV;
    const float* S2 = (dir == 0 ? y : x) + b * NV;

    // ---- Phase A: decode merged argmin, residual keys into LDS ----
    unsigned long long bv[8];
    #pragma unroll
    for (int k = 0; k < 8; ++k)
        bv[k] = best[(size_t)pair * N_ + k * 512 + tid];   // coalesced
    #pragma unroll
    for (int k = 0; k < 8; ++k) {
        const int q   = k * 512 + tid;
        const int idx = (int)(unsigned)(bv[k] & 0xFFFFFFFFull);
        float rx = S1[q * 3 + 0] - S2[idx * 3 + 0];
        float ry = S1[q * 3 + 1] - S2[idx * 3 + 1];
        float rz = S1[q * 3 + 2] - S2[idx * 3 + 2];
        keys[q * 3 + 0] = f2k(rx);
        keys[q * 3 + 1] = f2k(ry);
        keys[q * 3 + 2] = f2k(rz);
    }
    if (tid < 4) {
        const float Qs[4] = {0.05f, 0.95f, 0.25f, 0.75f};
        s_prefix[tid] = 0u;
        s_want[tid]   = (int)floorf(Qs[tid] * (float)(NV - 1));
    }
    __syncthreads();

    // ---- Phase B: 4 radix passes (uint4-vectorized element scans) ----
    const uint4* k4 = (const uint4*)keys;   // NV/4 = 3072 = 6 * 512 exact
    #pragma unroll 1
    for (int pass = 0; pass < 4; ++pass) {
        const int shift = 24 - 8 * pass;
        ((int*)hist8)[tid]        = 0;      // 2048 ints, 4 stores/thread
        ((int*)hist8)[tid + 512]  = 0;
        ((int*)hist8)[tid + 1024] = 0;
        ((int*)hist8)[tid + 1536] = 0;
        __syncthreads();

        if (pass == 0) {
            int* h = hist8[wid];            // wave-private copy
            for (int i = tid; i < NV / 4; i += 512) {
                uint4 kv = k4[i];
                atomicAdd(&h[kv.x >> 24], 1);
                atomicAdd(&h[kv.y >> 24], 1);
                atomicAdd(&h[kv.z >> 24], 1);
                atomicAdd(&h[kv.w >> 24], 1);
            }
        } else {
            const unsigned pmask = 0xFFFFFFFFu << (32 - 8 * pass);
            const unsigned pf0 = s_prefix[0], pf1 = s_prefix[1];
            const unsigned pf2 = s_prefix[2], pf3 = s_prefix[3];
            for (int i = tid; i < NV / 4; i += 512) {
                uint4 kv = k4[i];
                const unsigned ks[4] = {kv.x, kv.y, kv.z, kv.w};
                #pragma unroll
                for (int u = 0; u < 4; ++u) {
                    const unsigned k  = ks[u];
                    const unsigned kp = k & pmask;
                    const int bin = (int)((k >> shift) & 255u);
                    if (kp == pf0) atomicAdd(&hist8[0][bin], 1);
                    if (kp == pf1) atomicAdd(&hist8[1][bin], 1);
                    if (kp == pf2) atomicAdd(&hist8[2][bin], 1);
                    if (kp == pf3) atomicAdd(&hist8[3][bin], 1);
                }
            }
        }
        __syncthreads();

        // selection: wave t (t<4) scans quantile t's histogram
        if (wid < 4) {
            int c0 = 0, c1 = 0, c2 = 0, c3 = 0;
            if (pass == 0) {
                #pragma unroll
                for (int cp = 0; cp < 8; ++cp) {
                    c0 += hist8[cp][lane * 4 + 0]; c1 += hist8[cp][lane * 4 + 1];
                    c2 += hist8[cp][lane * 4 + 2]; c3 += hist8[cp][lane * 4 + 3];
                }
            } else {
                c0 = hist8[wid][lane * 4 + 0]; c1 = hist8[wid][lane * 4 + 1];
                c2 = hist8[wid][lane * 4 + 2]; c3 = hist8[wid][lane * 4 + 3];
            }
            const int want = s_want[wid];
            int s = c0 + c1 + c2 + c3;
            int pre = s;
            #pragma unroll
            for (int off = 1; off < 64; off <<= 1) {
                int u = __shfl_up(pre, off);
                if (lane >= off) pre += u;
            }
            const int excl = pre - s;
            const bool hit = (want >= excl) && (want < excl + s);
            unsigned long long m = __ballot(hit);
            const int hl = (int)(__ffsll(m) - 1);
            if (lane == hl) {
                int w = want - excl;
                int sel;
                if      (w < c0)           { sel = lane * 4 + 0; }
                else if (w < c0 + c1)      { sel = lane * 4 + 1; w -= c0; }
                else if (w < c0 + c1 + c2) { sel = lane * 4 + 2; w -= c0 + c1; }
                else                       { sel = lane * 4 + 3; w -= c0 + c1 + c2; }
                s_prefix[wid] |= ((unsigned)sel) << shift;
                s_want[wid] = w;
            }
        }
        __syncthreads();
    }

    // ---- Phase C: count(<=key0) and min(>key0) for all 4 quantiles ----
    if (tid < 4) { s_cnt[tid] = 0; s_mn[tid] = 0xFFFFFFFFu; }
    __syncthreads();
    const unsigned kq0 = s_prefix[0], kq1 = s_prefix[1];
    const unsigned kq2 = s_prefix[2], kq3 = s_prefix[3];
    int cnt0 = 0, cnt1 = 0, cnt2 = 0, cnt3 = 0;
    unsigned mn0 = 0xFFFFFFFFu, mn1 = 0xFFFFFFFFu, mn2 = 0xFFFFFFFFu, mn3 = 0xFFFFFFFFu;
    for (int i = tid; i < NV / 4; i += 512) {
        uint4 kv = k4[i];
        const unsigned ks[4] = {kv.x, kv.y, kv.z, kv.w};
        #pragma unroll
        for (int u = 0; u < 4; ++u) {
            const unsigned k = ks[u];
            if (k <= kq0) cnt0++; else if (k < mn0) mn0 = k;
            if (k <= kq1) cnt1++; else if (k < mn1) mn1 = k;
            if (k <= kq2) cnt2++; else if (k < mn2) mn2 = k;
            if (k <= kq3) cnt3++; else if (k < mn3) mn3 = k;
        }
    }
    #pragma unroll
    for (int off = 32; off > 0; off >>= 1) {
        cnt0 += __shfl_down(cnt0, off); cnt1 += __shfl_down(cnt1, off);
        cnt2 += __shfl_down(cnt2, off); cnt3 += __shfl_down(cnt3, off);
        unsigned u0 = __shfl_down(mn0, off); mn0 = u0 < mn0 ? u0 : mn0;
        unsigned u1 = __shfl_down(mn1, off); mn1 = u1 < mn1 ? u1 : mn1;
        unsigned u2 = __shfl_down(mn2, off); mn2 = u2 < mn2 ? u2 : mn2;
        unsigned u3 = __shfl_down(mn3, off); mn3 = u3 < mn3 ? u3 : mn3;
    }
    if (lane == 0) {
        atomicAdd(&s_cnt[0], cnt0); atomicMin(&s_mn[0], mn0);
        atomicAdd(&s_cnt[1], cnt1); atomicMin(&s_mn[1], mn1);
        atomicAdd(&s_cnt[2], cnt2); atomicMin(&s_mn[2], mn2);
        atomicAdd(&s_cnt[3], cnt3); atomicMin(&s_mn[3], mn3);
    }
    __syncthreads();
    if (tid < 4) {
        const float Qs[4] = {0.05f, 0.95f, 0.25f, 0.75f};
        const float pos = Qs[tid] * (float)(NV - 1);
        const int   k0  = (int)floorf(pos);
        const float fr  = pos - (float)k0;
        const float v0  = k2f(s_prefix[tid]);
        const float v1  = (s_cnt[tid] >= k0 + 2) ? v0 : k2f(s_mn[tid]);
        s_qv[tid] = v0 + fr * (v1 - v0);
    }
    __syncthreads();
    const float q0 = s_qv[0], q1 = s_qv[1], q2 = s_qv[2], q3 = s_qv[3];

    // ---- Phase D: masked two-pass mean/std from LDS keys ----
    float cb = 0.f, sb = 0.f, ce = 0.f, se = 0.f;
    for (int i = tid; i < NV / 4; i += 512) {
        uint4 kv = k4[i];
        const unsigned ks[4] = {kv.x, kv.y, kv.z, kv.w};
        #pragma unroll
        for (int u = 0; u < 4; ++u) {
            const float val = k2f(ks[u]);
            if ((val < q0) || (val > q1)) { cb += 1.f; sb += val; }
            if ((val > q2) && (val < q3)) { ce += 1.f; se += val; }
        }
    }
    #pragma unroll
    for (int off = 32; off > 0; off >>= 1) {
        cb += __shfl_down(cb, off); sb += __shfl_down(sb, off);
        ce += __shfl_down(ce, off); se += __shfl_down(se, off);
    }
    if (lane == 0) {
        red[wid * 4 + 0] = cb; red[wid * 4 + 1] = sb;
        red[wid * 4 + 2] = ce; red[wid * 4 + 3] = se;
    }
    __syncthreads();
    if (tid == 0) {
        float tcb = 0.f, tsb = 0.f, tce = 0.f, tse = 0.f;
        for (int w = 0; w < 8; ++w) {
            tcb += red[w * 4 + 0]; tsb += red[w * 4 + 1];
            tce += red[w * 4 + 2]; tse += red[w * 4 + 3];
        }
        sh[0] = tsb / tcb;  sh[1] = tse / tce;   // means
        sh[2] = tcb;        sh[3] = tce;         // counts
    }
    __syncthreads();
    const float mean_b = sh[0], mean_e = sh[1];
    const float nb = sh[2], ne = sh[3];

    float vb = 0.f, ve = 0.f;
    for (int i = tid; i < NV / 4; i += 512) {
        uint4 kv = k4[i];
        const unsigned ks[4] = {kv.x, kv.y, kv.z, kv.w};
        #pragma unroll
        for (int u = 0; u < 4; ++u) {
            const float val = k2f(ks[u]);
            if ((val < q0) || (val > q1)) { float d = val - mean_b; vb += d * d; }
            if ((val > q2) && (val < q3)) { float d = val - mean_e; ve += d * d; }
        }
    }
    #pragma unroll
    for (int off = 32; off > 0; off >>= 1) {
        vb += __shfl_down(vb, off);
        ve += __shfl_down(ve, off);
    }
    __syncthreads();
    if (lane == 0) { red[wid * 2 + 0] = vb; red[wid * 2 + 1] = ve; }
    __syncthreads();
    if (tid == 0) {
        float tvb = 0.f, tve = 0.f;
        for (int w = 0; w < 8; ++w) { tvb += red[w * 2 + 0]; tve += red[w * 2 + 1]; }
        stats[pair * 2 + 0] = sqrtf(tvb / (nb - 1.f));   // unbiased std, begin
        stats[pair * 2 + 1] = sqrtf(tve / (ne - 1.f));   // unbiased std, end
    }
}

// ---------------------------------------------------------------------------
// Kernel 3: per-batch max over directions, mean over batches.
// ---------------------------------------------------------------------------
__global__ void final_kernel(const float* __restrict__ stats, float* __restrict__ out) {
    if (threadIdx.x == 0 && blockIdx.x == 0) {
        float sb = 0.f, se = 0.f;
        for (int b = 0; b < B_; ++b) {
            float b1 = stats[(b * 2 + 0) * 2 + 0];
            float b2 = stats[(b * 2 + 1) * 2 + 0];
            float e1 = stats[(b * 2 + 0) * 2 + 1];
            float e2 = stats[(b * 2 + 1) * 2 + 1];
            sb += fmaxf(b1, b2);
            se += fmaxf(e1, e2);
        }
        out[0] = sb / (float)B_;
        out[1] = se / (float)B_;
    }
}

extern "C" void kernel_launch(void* const* d_in, const int* in_sizes, int n_in,
                              void* d_out, int out_size, void* d_ws, size_t ws_size,
                              hipStream_t stream) {
    const float* x = (const float*)d_in[0];
    const float* y = (const float*)d_in[1];
    float* out = (float*)d_out;

    unsigned long long* best = (unsigned long long*)d_ws;   // 8*N_ u64 = 256 KB
    float* stats = (float*)(best + (size_t)8 * N_);         // 16 floats

    init_best_kernel<<<(8 * N_) / 256, 256, 0, stream>>>(best);
    nn_atomic_kernel<<<dim3(NCCH, 2, 8), 256, 0, stream>>>(x, y, best);
    fused_tail_kernel<<<8, 512, 0, stream>>>(x, y, best, stats);
    final_kernel<<<1, 64, 0, stream>>>(stats, out);
}

// Round 10
// 70.386 us; speedup vs baseline: 2.5421x; 1.3235x over previous
//
#include <hip/hip_runtime.h>
#include <math.h>

// Problem constants (fixed by the reference: B=4, N=4096, D=3)
constexpr int B_  = 4;
constexpr int N_  = 4096;
constexpr int NV  = N_ * 3;      // 12288 flattened residual elements per (batch,dir)
constexpr int QPT = 8;           // queries per thread in the NN kernel

// float <-> monotonic uint key (order-preserving bijection on finite floats)
__device__ inline unsigned f2k(float f) {
    unsigned b = __float_as_uint(f);
    return b ^ ((unsigned)((int)b >> 31) | 0x80000000u);
}
__device__ inline float k2f(unsigned k) {
    unsigned b = (k & 0x80000000u) ? (k ^ 0x80000000u) : ~k;
    return __uint_as_float(b);
}

// ---------------------------------------------------------------------------
// Kernel 1: partial NN over a candidate chunk, 8 queries per thread.
// grid = (NCCH cand chunks, 2 query chunks, 8 pairs), block = 256.
// LDS candidates prescaled {-2bx,-2by,-2bz,|b|^2} -> d2 in 3 FMAs.
// One ds_read_b128 per candidate feeds 8 query updates (LDS amortized 8x).
// Strict '<' keeps the FIRST minimal index (jnp.argmin tie-break).
// Plain coalesced float4 partial stores -- no atomics, no contention.
// ---------------------------------------------------------------------------
template <int NCCH>
__global__ __launch_bounds__(256) void nn_partial_kernel(const float* __restrict__ x,
                                                         const float* __restrict__ y,
                                                         float2* __restrict__ part) {
    constexpr int CCH = N_ / NCCH;
    __shared__ float4 s2[CCH];
    const int pair = blockIdx.z;
    const int b    = pair >> 1;
    const int dir  = pair & 1;              // 0: S1=x,S2=y ; 1: S1=y,S2=x
    const float* S1 = (dir == 0 ? x : y) + b * NV;
    const float* S2 = (dir == 0 ? y : x) + b * NV;
    const int cbase = blockIdx.x * CCH;

    for (int j = threadIdx.x; j < CCH; j += 256) {
        float bx = S2[(cbase + j) * 3 + 0];
        float by = S2[(cbase + j) * 3 + 1];
        float bz = S2[(cbase + j) * 3 + 2];
        s2[j] = make_float4(-2.f * bx, -2.f * by, -2.f * bz,
                            bx * bx + by * by + bz * bz);
    }
    __syncthreads();

    // 8 contiguous queries per thread: 24 floats = 6 aligned float4 loads.
    const int q0 = blockIdx.y * 2048 + threadIdx.x * QPT;
    float ax[QPT], ay[QPT], az[QPT];
    {
        const float4* p4 = (const float4*)(S1 + q0 * 3);
        float4 v[6];
        #pragma unroll
        for (int i = 0; i < 6; ++i) v[i] = p4[i];
        const float* f = (const float*)v;
        #pragma unroll
        for (int k = 0; k < QPT; ++k) {
            ax[k] = f[k * 3 + 0]; ay[k] = f[k * 3 + 1]; az[k] = f[k * 3 + 2];
        }
    }

    float bd[QPT]; int idx[QPT];
    #pragma unroll
    for (int k = 0; k < QPT; ++k) { bd[k] = INFINITY; idx[k] = 0; }

    #pragma unroll 2
    for (int j = 0; j < CCH; ++j) {
        float4 c = s2[j];                   // uniform address broadcast
        const int jg = cbase + j;
        #pragma unroll
        for (int k = 0; k < QPT; ++k) {
            // d2 = |b|^2 - 2 a.b  (3 FMAs on prescaled candidate)
            float d2 = fmaf(ax[k], c.x, fmaf(ay[k], c.y, fmaf(az[k], c.z, c.w)));
            if (d2 < bd[k]) idx[k] = jg;    // v_cmp + v_cndmask
            bd[k] = fminf(d2, bd[k]);       // v_min
        }
    }

    float2 o[QPT];
    #pragma unroll
    for (int k = 0; k < QPT; ++k) o[k] = make_float2(bd[k], (float)idx[k]);
    float4* op = (float4*)(part + (size_t)(pair * NCCH + blockIdx.x) * N_ + q0);
    #pragma unroll
    for (int i = 0; i < QPT / 2; ++i) op[i] = ((const float4*)o)[i];
}

// ---------------------------------------------------------------------------
// Kernel 2: parallel merge. grid = (N_/256, 8 pairs), block = 256.
// NCCH fully unrolled -> 32 INDEPENDENT dwordx2 loads (no latency chain),
// ascending chunk order + strict '<' == global first-index argmin.
// Writes monotonic keys component-major (keys[pair][comp*N+q]) -- fully
// coalesced; quantile/std are order-invariant over the flattened set.
// ---------------------------------------------------------------------------
template <int NCCH>
__global__ __launch_bounds__(256) void merge_keys_kernel(const float* __restrict__ x,
                                                         const float* __restrict__ y,
                                                         const float2* __restrict__ part,
                                                         unsigned* __restrict__ keys) {
    const int pair = blockIdx.y;
    const int b    = pair >> 1;
    const int dir  = pair & 1;
    const float* S1 = (dir == 0 ? x : y) + b * NV;
    const float* S2 = (dir == 0 ? y : x) + b * NV;
    const int q = blockIdx.x * 256 + threadIdx.x;

    float best = INFINITY;
    int bidx = 0;
    #pragma unroll
    for (int c = 0; c < NCCH; ++c) {
        float2 p = part[(size_t)(pair * NCCH + c) * N_ + q];
        if (p.x < best) { best = p.x; bidx = (int)p.y; }
    }
    unsigned* kp = keys + (size_t)pair * NV;
    kp[0 * N_ + q] = f2k(S1[q * 3 + 0] - S2[bidx * 3 + 0]);
    kp[1 * N_ + q] = f2k(S1[q * 3 + 1] - S2[bidx * 3 + 1]);
    kp[2 * N_ + q] = f2k(S1[q * 3 + 2] - S2[bidx * 3 + 2]);
}

// ---------------------------------------------------------------------------
// Kernel 3 (TAIL): one block per (batch,dir) pair, 512 threads.
//   A: stream keys into LDS (6 uint4 loads/thread, coalesced).
//   B: 4x 8-bit MSD radix-select for all four quantile order-stats at once
//      (uint4-vectorized scans; pass-1 hist has 8 wave-private copies).
//   C: fused count(<=key0)/min(>key0) -> linear-interp quantiles
//      (positions in fp32, identical to jnp.quantile).
//   D: two-pass masked mean/std from LDS keys (k2f exact inverse).
// ---------------------------------------------------------------------------
__global__ __launch_bounds__(512) void tail_kernel(const unsigned* __restrict__ gkeys,
                                                   float* __restrict__ stats) {
    __shared__ unsigned keys[NV];           // 48 KB
    __shared__ int hist8[8][256];           // 8 KB
    __shared__ unsigned s_prefix[4];
    __shared__ int s_want[4];
    __shared__ int s_cnt[4];
    __shared__ unsigned s_mn[4];
    __shared__ float s_qv[4];
    __shared__ float red[32];
    __shared__ float sh[8];

    const int pair = blockIdx.x;
    const int tid  = threadIdx.x;
    const int lane = tid & 63;
    const int wid  = tid >> 6;              // 8 waves

    // ---- Phase A: stream keys into LDS ----
    const uint4* g4 = (const uint4*)(gkeys + (size_t)pair * NV);
    uint4* l4w = (uint4*)keys;
    #pragma unroll
    for (int i = 0; i < 6; ++i)             // NV/4 = 3072 = 6 * 512 exact
        l4w[i * 512 + tid] = g4[i * 512 + tid];
    if (tid < 4) {
        const float Qs[4] = {0.05f, 0.95f, 0.25f, 0.75f};
        s_prefix[tid] = 0u;
        s_want[tid]   = (int)floorf(Qs[tid] * (float)(NV - 1));
    }
    __syncthreads();

    // ---- Phase B: 4 radix passes (uint4-vectorized element scans) ----
    const uint4* k4 = (const uint4*)keys;
    #pragma unroll 1
    for (int pass = 0; pass < 4; ++pass) {
        const int shift = 24 - 8 * pass;
        ((int*)hist8)[tid]        = 0;      // 2048 ints, 4 stores/thread
        ((int*)hist8)[tid + 512]  = 0;
        ((int*)hist8)[tid + 1024] = 0;
        ((int*)hist8)[tid + 1536] = 0;
        __syncthreads();

        if (pass == 0) {
            int* h = hist8[wid];            // wave-private copy
            for (int i = tid; i < NV / 4; i += 512) {
                uint4 kv = k4[i];
                atomicAdd(&h[kv.x >> 24], 1);
                atomicAdd(&h[kv.y >> 24], 1);
                atomicAdd(&h[kv.z >> 24], 1);
                atomicAdd(&h[kv.w >> 24], 1);
            }
        } else {
            const unsigned pmask = 0xFFFFFFFFu << (32 - 8 * pass);
            const unsigned pf0 = s_prefix[0], pf1 = s_prefix[1];
            const unsigned pf2 = s_prefix[2], pf3 = s_prefix[3];
            for (int i = tid; i < NV / 4; i += 512) {
                uint4 kv = k4[i];
                const unsigned ks[4] = {kv.x, kv.y, kv.z, kv.w};
                #pragma unroll
                for (int u = 0; u < 4; ++u) {
                    const unsigned k  = ks[u];
                    const unsigned kp = k & pmask;
                    const int bin = (int)((k >> shift) & 255u);
                    if (kp == pf0) atomicAdd(&hist8[0][bin], 1);
                    if (kp == pf1) atomicAdd(&hist8[1][bin], 1);
                    if (kp == pf2) atomicAdd(&hist8[2][bin], 1);
                    if (kp == pf3) atomicAdd(&hist8[3][bin], 1);
                }
            }
        }
        __syncthreads();

        // selection: wave t (t<4) scans quantile t's histogram
        if (wid < 4) {
            int c0 = 0, c1 = 0, c2 = 0, c3 = 0;
            if (pass == 0) {
                #pragma unroll
                for (int cp = 0; cp < 8; ++cp) {
                    c0 += hist8[cp][lane * 4 + 0]; c1 += hist8[cp][lane * 4 + 1];
                    c2 += hist8[cp][lane * 4 + 2]; c3 += hist8[cp][lane * 4 + 3];
                }
            } else {
                c0 = hist8[wid][lane * 4 + 0]; c1 = hist8[wid][lane * 4 + 1];
                c2 = hist8[wid][lane * 4 + 2]; c3 = hist8[wid][lane * 4 + 3];
            }
            const int want = s_want[wid];
            int s = c0 + c1 + c2 + c3;
            int pre = s;
            #pragma unroll
            for (int off = 1; off < 64; off <<= 1) {
                int u = __shfl_up(pre, off);
                if (lane >= off) pre += u;
            }
            const int excl = pre - s;
            const bool hit = (want >= excl) && (want < excl + s);
            unsigned long long m = __ballot(hit);
            const int hl = (int)(__ffsll(m) - 1);
            if (lane == hl) {
                int w = want - excl;
                int sel;
                if      (w < c0)           { sel = lane * 4 + 0; }
                else if (w < c0 + c1)      { sel = lane * 4 + 1; w -= c0; }
                else if (w < c0 + c1 + c2) { sel = lane * 4 + 2; w -= c0 + c1; }
                else                       { sel = lane * 4 + 3; w -= c0 + c1 + c2; }
                s_prefix[wid] |= ((unsigned)sel) << shift;
                s_want[wid] = w;
            }
        }
        __syncthreads();
    }

    // ---- Phase C: count(<=key0) and min(>key0) for all 4 quantiles ----
    if (tid < 4) { s_cnt[tid] = 0; s_mn[tid] = 0xFFFFFFFFu; }
    __syncthreads();
    const unsigned kq0 = s_prefix[0], kq1 = s_prefix[1];
    const unsigned kq2 = s_prefix[2], kq3 = s_prefix[3];
    int cnt0 = 0, cnt1 = 0, cnt2 = 0, cnt3 = 0;
    unsigned mn0 = 0xFFFFFFFFu, mn1 = 0xFFFFFFFFu, mn2 = 0xFFFFFFFFu, mn3 = 0xFFFFFFFFu;
    for (int i = tid; i < NV / 4; i += 512) {
        uint4 kv = k4[i];
        const unsigned ks[4] = {kv.x, kv.y, kv.z, kv.w};
        #pragma unroll
        for (int u = 0; u < 4; ++u) {
            const unsigned k = ks[u];
            if (k <= kq0) cnt0++; else if (k < mn0) mn0 = k;
            if (k <= kq1) cnt1++; else if (k < mn1) mn1 = k;
            if (k <= kq2) cnt2++; else if (k < mn2) mn2 = k;
            if (k <= kq3) cnt3++; else if (k < mn3) mn3 = k;
        }
    }
    #pragma unroll
    for (int off = 32; off > 0; off >>= 1) {
        cnt0 += __shfl_down(cnt0, off); cnt1 += __shfl_down(cnt1, off);
        cnt2 += __shfl_down(cnt2, off); cnt3 += __shfl_down(cnt3, off);
        unsigned u0 = __shfl_down(mn0, off); mn0 = u0 < mn0 ? u0 : mn0;
        unsigned u1 = __shfl_down(mn1, off); mn1 = u1 < mn1 ? u1 : mn1;
        unsigned u2 = __shfl_down(mn2, off); mn2 = u2 < mn2 ? u2 : mn2;
        unsigned u3 = __shfl_down(mn3, off); mn3 = u3 < mn3 ? u3 : mn3;
    }
    if (lane == 0) {
        atomicAdd(&s_cnt[0], cnt0); atomicMin(&s_mn[0], mn0);
        atomicAdd(&s_cnt[1], cnt1); atomicMin(&s_mn[1], mn1);
        atomicAdd(&s_cnt[2], cnt2); atomicMin(&s_mn[2], mn2);
        atomicAdd(&s_cnt[3], cnt3); atomicMin(&s_mn[3], mn3);
    }
    __syncthreads();
    if (tid < 4) {
        const float Qs[4] = {0.05f, 0.95f, 0.25f, 0.75f};
        const float pos = Qs[tid] * (float)(NV - 1);
        const int   k0  = (int)floorf(pos);
        const float fr  = pos - (float)k0;
        const float v0  = k2f(s_prefix[tid]);
        const float v1  = (s_cnt[tid] >= k0 + 2) ? v0 : k2f(s_mn[tid]);
        s_qv[tid] = v0 + fr * (v1 - v0);
    }
    __syncthreads();
    const float q0 = s_qv[0], q1 = s_qv[1], q2 = s_qv[2], q3 = s_qv[3];

    // ---- Phase D: masked two-pass mean/std from LDS keys ----
    float cb = 0.f, sb = 0.f, ce = 0.f, se = 0.f;
    for (int i = tid; i < NV / 4; i += 512) {
        uint4 kv = k4[i];
        const unsigned ks[4] = {kv.x, kv.y, kv.z, kv.w};
        #pragma unroll
        for (int u = 0; u < 4; ++u) {
            const float val = k2f(ks[u]);
            if ((val < q0) || (val > q1)) { cb += 1.f; sb += val; }
            if ((val > q2) && (val < q3)) { ce += 1.f; se += val; }
        }
    }
    #pragma unroll
    for (int off = 32; off > 0; off >>= 1) {
        cb += __shfl_down(cb, off); sb += __shfl_down(sb, off);
        ce += __shfl_down(ce, off); se += __shfl_down(se, off);
    }
    if (lane == 0) {
        red[wid * 4 + 0] = cb; red[wid * 4 + 1] = sb;
        red[wid * 4 + 2] = ce; red[wid * 4 + 3] = se;
    }
    __syncthreads();
    if (tid == 0) {
        float tcb = 0.f, tsb = 0.f, tce = 0.f, tse = 0.f;
        for (int w = 0; w < 8; ++w) {
            tcb += red[w * 4 + 0]; tsb += red[w * 4 + 1];
            tce += red[w * 4 + 2]; tse += red[w * 4 + 3];
        }
        sh[0] = tsb / tcb;  sh[1] = tse / tce;   // means
        sh[2] = tcb;        sh[3] = tce;         // counts
    }
    __syncthreads();
    const float mean_b = sh[0], mean_e = sh[1];
    const float nb = sh[2], ne = sh[3];

    float vb = 0.f, ve = 0.f;
    for (int i = tid; i < NV / 4; i += 512) {
        uint4 kv = k4[i];
        const unsigned ks[4] = {kv.x, kv.y, kv.z, kv.w};
        #pragma unroll
        for (int u = 0; u < 4; ++u) {
            const float val = k2f(ks[u]);
            if ((val < q0) || (val > q1)) { float d = val - mean_b; vb += d * d; }
            if ((val > q2) && (val < q3)) { float d = val - mean_e; ve += d * d; }
        }
    }
    #pragma unroll
    for (int off = 32; off > 0; off >>= 1) {
        vb += __shfl_down(vb, off);
        ve += __shfl_down(ve, off);
    }
    __syncthreads();
    if (lane == 0) { red[wid * 2 + 0] = vb; red[wid * 2 + 1] = ve; }
    __syncthreads();
    if (tid == 0) {
        float tvb = 0.f, tve = 0.f;
        for (int w = 0; w < 8; ++w) { tvb += red[w * 2 + 0]; tve += red[w * 2 + 1]; }
        stats[pair * 2 + 0] = sqrtf(tvb / (nb - 1.f));   // unbiased std, begin
        stats[pair * 2 + 1] = sqrtf(tve / (ne - 1.f));   // unbiased std, end
    }
}

// ---------------------------------------------------------------------------
// Kernel 4: per-batch max over directions, mean over batches.
// ---------------------------------------------------------------------------
__global__ void final_kernel(const float* __restrict__ stats, float* __restrict__ out) {
    if (threadIdx.x == 0 && blockIdx.x == 0) {
        float sb = 0.f, se = 0.f;
        for (int b = 0; b < B_; ++b) {
            float b1 = stats[(b * 2 + 0) * 2 + 0];
            float b2 = stats[(b * 2 + 1) * 2 + 0];
            float e1 = stats[(b * 2 + 0) * 2 + 1];
            float e2 = stats[(b * 2 + 1) * 2 + 1];
            sb += fmaxf(b1, b2);
            se += fmaxf(e1, e2);
        }
        out[0] = sb / (float)B_;
        out[1] = se / (float)B_;
    }
}

template <int NCCH>
static void run_pipeline(const float* x, const float* y, float2* part,
                         unsigned* keys, float* stats, float* out,
                         hipStream_t stream) {
    nn_partial_kernel<NCCH><<<dim3(NCCH, 2, 8), 256, 0, stream>>>(x, y, part);
    merge_keys_kernel<NCCH><<<dim3(N_ / 256, 8), 256, 0, stream>>>(x, y, part, keys);
    tail_kernel<<<8, 512, 0, stream>>>(keys, stats);
    final_kernel<<<1, 64, 0, stream>>>(stats, out);
}

extern "C" void kernel_launch(void* const* d_in, const int* in_sizes, int n_in,
                              void* d_out, int out_size, void* d_ws, size_t ws_size,
                              hipStream_t stream) {
    const float* x = (const float*)d_in[0];
    const float* y = (const float*)d_in[1];
    float* out = (float*)d_out;

    // Workspace: [keys 384KB][stats 64B][part ...]
    unsigned* keys  = (unsigned*)d_ws;
    float*    stats = (float*)(keys + (size_t)8 * NV);
    float2*   part  = (float2*)(stats + 16);

    const size_t head   = ((size_t)8 * NV + 16) * sizeof(float);
    const size_t need32 = head + (size_t)8 * 32 * N_ * sizeof(float2);  // ~8.8 MB

    if (ws_size >= need32) {
        run_pipeline<32>(x, y, part, keys, stats, out, stream);
    } else {
        run_pipeline<8>(x, y, part, keys, stats, out, stream);
    }
}

// Round 11
// 70.217 us; speedup vs baseline: 2.5482x; 1.0024x over previous
//
#include <hip/hip_runtime.h>
#include <math.h>

// Problem constants (fixed by the reference: B=4, N=4096, D=3)
constexpr int B_  = 4;
constexpr int N_  = 4096;
constexpr int NV  = N_ * 3;      // 12288 flattened residual elements per (batch,dir)
constexpr int QPT = 8;           // queries per thread in the NN kernel
constexpr int TPB_TAIL = 1024;   // tail kernel block size

// float <-> monotonic uint key (order-preserving bijection on finite floats)
__device__ inline unsigned f2k(float f) {
    unsigned b = __float_as_uint(f);
    return b ^ ((unsigned)((int)b >> 31) | 0x80000000u);
}
__device__ inline float k2f(unsigned k) {
    unsigned b = (k & 0x80000000u) ? (k ^ 0x80000000u) : ~k;
    return __uint_as_float(b);
}

// ---------------------------------------------------------------------------
// Kernel 1: partial NN over a candidate chunk, 8 queries per thread.
// grid = (NCCH cand chunks, 2 query chunks, 8 pairs), block = 256.
// __launch_bounds__(256,2): we run exactly 2 blocks/CU (512 blocks, 256 CUs),
// so grant the compiler the full VGPR budget for the 8-query register tile.
// The empty volatile asm pins the staged candidate in VGPRs: the compiler
// cannot distribute the k-loop into per-query j-passes (that would duplicate
// a volatile asm's dynamic executions), so one ds_read_b128 per candidate is
// shared by all 8 query updates. (Round-9 evidence: without this, VGPR=32 ->
// compiler had split the loop, re-reading LDS 8x.)
// Strict '<' keeps the FIRST minimal index (jnp.argmin tie-break).
// ---------------------------------------------------------------------------
template <int NCCH>
__global__ __launch_bounds__(256, 2) void nn_partial_kernel(const float* __restrict__ x,
                                                            const float* __restrict__ y,
                                                            float2* __restrict__ part) {
    constexpr int CCH = N_ / NCCH;
    __shared__ float4 s2[CCH];
    const int pair = blockIdx.z;
    const int b    = pair >> 1;
    const int dir  = pair & 1;              // 0: S1=x,S2=y ; 1: S1=y,S2=x
    const float* S1 = (dir == 0 ? x : y) + b * NV;
    const float* S2 = (dir == 0 ? y : x) + b * NV;
    const int cbase = blockIdx.x * CCH;

    for (int j = threadIdx.x; j < CCH; j += 256) {
        float bx = S2[(cbase + j) * 3 + 0];
        float by = S2[(cbase + j) * 3 + 1];
        float bz = S2[(cbase + j) * 3 + 2];
        s2[j] = make_float4(-2.f * bx, -2.f * by, -2.f * bz,
                            bx * bx + by * by + bz * bz);
    }
    __syncthreads();

    // 8 contiguous queries per thread: 24 floats = 6 aligned float4 loads.
    const int q0 = blockIdx.y * 2048 + threadIdx.x * QPT;
    float ax[QPT], ay[QPT], az[QPT];
    {
        const float4* p4 = (const float4*)(S1 + q0 * 3);
        float4 v[6];
        #pragma unroll
        for (int i = 0; i < 6; ++i) v[i] = p4[i];
        const float* f = (const float*)v;
        #pragma unroll
        for (int k = 0; k < QPT; ++k) {
            ax[k] = f[k * 3 + 0]; ay[k] = f[k * 3 + 1]; az[k] = f[k * 3 + 2];
        }
    }

    float bd[QPT]; int idx[QPT];
    #pragma unroll
    for (int k = 0; k < QPT; ++k) { bd[k] = INFINITY; idx[k] = 0; }

    for (int j = 0; j < CCH; ++j) {
        float4 c = s2[j];                   // one ds_read_b128, broadcast
        // Pin the candidate in registers; forbids per-query re-read.
        asm volatile("" : "+v"(c.x), "+v"(c.y), "+v"(c.z), "+v"(c.w));
        const int jg = cbase + j;
        #pragma unroll
        for (int k = 0; k < QPT; ++k) {
            // d2 = |b|^2 - 2 a.b  (3 FMAs on prescaled candidate)
            float d2 = fmaf(ax[k], c.x, fmaf(ay[k], c.y, fmaf(az[k], c.z, c.w)));
            if (d2 < bd[k]) idx[k] = jg;    // v_cmp + v_cndmask
            bd[k] = fminf(d2, bd[k]);       // v_min
        }
    }

    float2 o[QPT];
    #pragma unroll
    for (int k = 0; k < QPT; ++k) o[k] = make_float2(bd[k], (float)idx[k]);
    float4* op = (float4*)(part + (size_t)(pair * NCCH + blockIdx.x) * N_ + q0);
    #pragma unroll
    for (int i = 0; i < QPT / 2; ++i) op[i] = ((const float4*)o)[i];
}

// ---------------------------------------------------------------------------
// Kernel 2: parallel merge. grid = (N_/256, 8 pairs), block = 256.
// NCCH fully unrolled -> independent dwordx2 loads (no latency chain),
// ascending chunk order + strict '<' == global first-index argmin.
// Writes monotonic keys component-major (keys[pair][comp*N+q]) -- fully
// coalesced; quantile/std are order-invariant over the flattened set.
// ---------------------------------------------------------------------------
template <int NCCH>
__global__ __launch_bounds__(256) void merge_keys_kernel(const float* __restrict__ x,
                                                         const float* __restrict__ y,
                                                         const float2* __restrict__ part,
                                                         unsigned* __restrict__ keys) {
    const int pair = blockIdx.y;
    const int b    = pair >> 1;
    const int dir  = pair & 1;
    const float* S1 = (dir == 0 ? x : y) + b * NV;
    const float* S2 = (dir == 0 ? y : x) + b * NV;
    const int q = blockIdx.x * 256 + threadIdx.x;

    float best = INFINITY;
    int bidx = 0;
    #pragma unroll
    for (int c = 0; c < NCCH; ++c) {
        float2 p = part[(size_t)(pair * NCCH + c) * N_ + q];
        if (p.x < best) { best = p.x; bidx = (int)p.y; }
    }
    unsigned* kp = keys + (size_t)pair * NV;
    kp[0 * N_ + q] = f2k(S1[q * 3 + 0] - S2[bidx * 3 + 0]);
    kp[1 * N_ + q] = f2k(S1[q * 3 + 1] - S2[bidx * 3 + 1]);
    kp[2 * N_ + q] = f2k(S1[q * 3 + 2] - S2[bidx * 3 + 2]);
}

// ---------------------------------------------------------------------------
// Kernel 3 (TAIL): one block per (batch,dir) pair, 1024 threads (16 waves).
//   A: stream keys into LDS (3 uint4 loads/thread, coalesced).
//   B: 4x 8-bit MSD radix-select for all four quantile order-stats at once
//      (uint4-vectorized scans; pass-1 hist has 8 wave-group-private copies).
//   C: fused count(<=key0)/min(>key0) -> linear-interp quantiles
//      (positions in fp32, identical to jnp.quantile).
//   D: two-pass masked mean/std from LDS keys (k2f exact inverse).
// ---------------------------------------------------------------------------
__global__ __launch_bounds__(TPB_TAIL) void tail_kernel(const unsigned* __restrict__ gkeys,
                                                        float* __restrict__ stats) {
    __shared__ unsigned keys[NV];           // 48 KB
    __shared__ int hist8[8][256];           // 8 KB
    __shared__ unsigned s_prefix[4];
    __shared__ int s_want[4];
    __shared__ int s_cnt[4];
    __shared__ unsigned s_mn[4];
    __shared__ float s_qv[4];
    __shared__ float red[64];
    __shared__ float sh[8];

    const int pair = blockIdx.x;
    const int tid  = threadIdx.x;
    const int lane = tid & 63;
    const int wid  = tid >> 6;              // 16 waves

    // ---- Phase A: stream keys into LDS ----
    const uint4* g4 = (const uint4*)(gkeys + (size_t)pair * NV);
    uint4* l4w = (uint4*)keys;
    #pragma unroll
    for (int i = 0; i < 3; ++i)             // NV/4 = 3072 = 3 * 1024 exact
        l4w[i * TPB_TAIL + tid] = g4[i * TPB_TAIL + tid];
    if (tid < 4) {
        const float Qs[4] = {0.05f, 0.95f, 0.25f, 0.75f};
        s_prefix[tid] = 0u;
        s_want[tid]   = (int)floorf(Qs[tid] * (float)(NV - 1));
    }
    __syncthreads();

    // ---- Phase B: 4 radix passes (uint4-vectorized element scans) ----
    const uint4* k4 = (const uint4*)keys;
    #pragma unroll 1
    for (int pass = 0; pass < 4; ++pass) {
        const int shift = 24 - 8 * pass;
        ((int*)hist8)[tid]             = 0; // 2048 ints, 2 stores/thread
        ((int*)hist8)[tid + TPB_TAIL]  = 0;
        __syncthreads();

        if (pass == 0) {
            int* h = hist8[wid & 7];        // wave-group-private copy
            for (int i = tid; i < NV / 4; i += TPB_TAIL) {
                uint4 kv = k4[i];
                atomicAdd(&h[kv.x >> 24], 1);
                atomicAdd(&h[kv.y >> 24], 1);
                atomicAdd(&h[kv.z >> 24], 1);
                atomicAdd(&h[kv.w >> 24], 1);
            }
        } else {
            const unsigned pmask = 0xFFFFFFFFu << (32 - 8 * pass);
            const unsigned pf0 = s_prefix[0], pf1 = s_prefix[1];
            const unsigned pf2 = s_prefix[2], pf3 = s_prefix[3];
            for (int i = tid; i < NV / 4; i += TPB_TAIL) {
                uint4 kv = k4[i];
                const unsigned ks[4] = {kv.x, kv.y, kv.z, kv.w};
                #pragma unroll
                for (int u = 0; u < 4; ++u) {
                    const unsigned k  = ks[u];
                    const unsigned kp = k & pmask;
                    const int bin = (int)((k >> shift) & 255u);
                    if (kp == pf0) atomicAdd(&hist8[0][bin], 1);
                    if (kp == pf1) atomicAdd(&hist8[1][bin], 1);
                    if (kp == pf2) atomicAdd(&hist8[2][bin], 1);
                    if (kp == pf3) atomicAdd(&hist8[3][bin], 1);
                }
            }
        }
        __syncthreads();

        // selection: wave t (t<4) scans quantile t's histogram
        if (wid < 4) {
            int c0 = 0, c1 = 0, c2 = 0, c3 = 0;
            if (pass == 0) {
                #pragma unroll
                for (int cp = 0; cp < 8; ++cp) {
                    c0 += hist8[cp][lane * 4 + 0]; c1 += hist8[cp][lane * 4 + 1];
                    c2 += hist8[cp][lane * 4 + 2]; c3 += hist8[cp][lane * 4 + 3];
                }
            } else {
                c0 = hist8[wid][lane * 4 + 0]; c1 = hist8[wid][lane * 4 + 1];
                c2 = hist8[wid][lane * 4 + 2]; c3 = hist8[wid][lane * 4 + 3];
            }
            const int want = s_want[wid];
            int s = c0 + c1 + c2 + c3;
            int pre = s;
            #pragma unroll
            for (int off = 1; off < 64; off <<= 1) {
                int u = __shfl_up(pre, off);
                if (lane >= off) pre += u;
            }
            const int excl = pre - s;
            const bool hit = (want >= excl) && (want < excl + s);
            unsigned long long m = __ballot(hit);
            const int hl = (int)(__ffsll(m) - 1);
            if (lane == hl) {
                int w = want - excl;
                int sel;
                if      (w < c0)           { sel = lane * 4 + 0; }
                else if (w < c0 + c1)      { sel = lane * 4 + 1; w -= c0; }
                else if (w < c0 + c1 + c2) { sel = lane * 4 + 2; w -= c0 + c1; }
                else                       { sel = lane * 4 + 3; w -= c0 + c1 + c2; }
                s_prefix[wid] |= ((unsigned)sel) << shift;
                s_want[wid] = w;
            }
        }
        __syncthreads();
    }

    // ---- Phase C: count(<=key0) and min(>key0) for all 4 quantiles ----
    if (tid < 4) { s_cnt[tid] = 0; s_mn[tid] = 0xFFFFFFFFu; }
    __syncthreads();
    const unsigned kq0 = s_prefix[0], kq1 = s_prefix[1];
    const unsigned kq2 = s_prefix[2], kq3 = s_prefix[3];
    int cnt0 = 0, cnt1 = 0, cnt2 = 0, cnt3 = 0;
    unsigned mn0 = 0xFFFFFFFFu, mn1 = 0xFFFFFFFFu, mn2 = 0xFFFFFFFFu, mn3 = 0xFFFFFFFFu;
    for (int i = tid; i < NV / 4; i += TPB_TAIL) {
        uint4 kv = k4[i];
        const unsigned ks[4] = {kv.x, kv.y, kv.z, kv.w};
        #pragma unroll
        for (int u = 0; u < 4; ++u) {
            const unsigned k = ks[u];
            if (k <= kq0) cnt0++; else if (k < mn0) mn0 = k;
            if (k <= kq1) cnt1++; else if (k < mn1) mn1 = k;
            if (k <= kq2) cnt2++; else if (k < mn2) mn2 = k;
            if (k <= kq3) cnt3++; else if (k < mn3) mn3 = k;
        }
    }
    #pragma unroll
    for (int off = 32; off > 0; off >>= 1) {
        cnt0 += __shfl_down(cnt0, off); cnt1 += __shfl_down(cnt1, off);
        cnt2 += __shfl_down(cnt2, off); cnt3 += __shfl_down(cnt3, off);
        unsigned u0 = __shfl_down(mn0, off); mn0 = u0 < mn0 ? u0 : mn0;
        unsigned u1 = __shfl_down(mn1, off); mn1 = u1 < mn1 ? u1 : mn1;
        unsigned u2 = __shfl_down(mn2, off); mn2 = u2 < mn2 ? u2 : mn2;
        unsigned u3 = __shfl_down(mn3, off); mn3 = u3 < mn3 ? u3 : mn3;
    }
    if (lane == 0) {
        atomicAdd(&s_cnt[0], cnt0); atomicMin(&s_mn[0], mn0);
        atomicAdd(&s_cnt[1], cnt1); atomicMin(&s_mn[1], mn1);
        atomicAdd(&s_cnt[2], cnt2); atomicMin(&s_mn[2], mn2);
        atomicAdd(&s_cnt[3], cnt3); atomicMin(&s_mn[3], mn3);
    }
    __syncthreads();
    if (tid < 4) {
        const float Qs[4] = {0.05f, 0.95f, 0.25f, 0.75f};
        const float pos = Qs[tid] * (float)(NV - 1);
        const int   k0  = (int)floorf(pos);
        const float fr  = pos - (float)k0;
        const float v0  = k2f(s_prefix[tid]);
        const float v1  = (s_cnt[tid] >= k0 + 2) ? v0 : k2f(s_mn[tid]);
        s_qv[tid] = v0 + fr * (v1 - v0);
    }
    __syncthreads();
    const float q0 = s_qv[0], q1 = s_qv[1], q2 = s_qv[2], q3 = s_qv[3];

    // ---- Phase D: masked two-pass mean/std from LDS keys ----
    float cb = 0.f, sb = 0.f, ce = 0.f, se = 0.f;
    for (int i = tid; i < NV / 4; i += TPB_TAIL) {
        uint4 kv = k4[i];
        const unsigned ks[4] = {kv.x, kv.y, kv.z, kv.w};
        #pragma unroll
        for (int u = 0; u < 4; ++u) {
            const float val = k2f(ks[u]);
            if ((val < q0) || (val > q1)) { cb += 1.f; sb += val; }
            if ((val > q2) && (val < q3)) { ce += 1.f; se += val; }
        }
    }
    #pragma unroll
    for (int off = 32; off > 0; off >>= 1) {
        cb += __shfl_down(cb, off); sb += __shfl_down(sb, off);
        ce += __shfl_down(ce, off); se += __shfl_down(se, off);
    }
    if (lane == 0) {
        red[wid * 4 + 0] = cb; red[wid * 4 + 1] = sb;
        red[wid * 4 + 2] = ce; red[wid * 4 + 3] = se;
    }
    __syncthreads();
    if (tid == 0) {
        float tcb = 0.f, tsb = 0.f, tce = 0.f, tse = 0.f;
        for (int w = 0; w < 16; ++w) {
            tcb += red[w * 4 + 0]; tsb += red[w * 4 + 1];
            tce += red[w * 4 + 2]; tse += red[w * 4 + 3];
        }
        sh[0] = tsb / tcb;  sh[1] = tse / tce;   // means
        sh[2] = tcb;        sh[3] = tce;         // counts
    }
    __syncthreads();
    const float mean_b = sh[0], mean_e = sh[1];
    const float nb = sh[2], ne = sh[3];

    float vb = 0.f, ve = 0.f;
    for (int i = tid; i < NV / 4; i += TPB_TAIL) {
        uint4 kv = k4[i];
        const unsigned ks[4] = {kv.x, kv.y, kv.z, kv.w};
        #pragma unroll
        for (int u = 0; u < 4; ++u) {
            const float val = k2f(ks[u]);
            if ((val < q0) || (val > q1)) { float d = val - mean_b; vb += d * d; }
            if ((val > q2) && (val < q3)) { float d = val - mean_e; ve += d * d; }
        }
    }
    #pragma unroll
    for (int off = 32; off > 0; off >>= 1) {
        vb += __shfl_down(vb, off);
        ve += __shfl_down(ve, off);
    }
    __syncthreads();
    if (lane == 0) { red[wid * 2 + 0] = vb; red[wid * 2 + 1] = ve; }
    __syncthreads();
    if (tid == 0) {
        float tvb = 0.f, tve = 0.f;
        for (int w = 0; w < 16; ++w) { tvb += red[w * 2 + 0]; tve += red[w * 2 + 1]; }
        stats[pair * 2 + 0] = sqrtf(tvb / (nb - 1.f));   // unbiased std, begin
        stats[pair * 2 + 1] = sqrtf(tve / (ne - 1.f));   // unbiased std, end
    }
}

// ---------------------------------------------------------------------------
// Kernel 4: per-batch max over directions, mean over batches.
// ---------------------------------------------------------------------------
__global__ void final_kernel(const float* __restrict__ stats, float* __restrict__ out) {
    if (threadIdx.x == 0 && blockIdx.x == 0) {
        float sb = 0.f, se = 0.f;
        for (int b = 0; b < B_; ++b) {
            float b1 = stats[(b * 2 + 0) * 2 + 0];
            float b2 = stats[(b * 2 + 1) * 2 + 0];
            float e1 = stats[(b * 2 + 0) * 2 + 1];
            float e2 = stats[(b * 2 + 1) * 2 + 1];
            sb += fmaxf(b1, b2);
            se += fmaxf(e1, e2);
        }
        out[0] = sb / (float)B_;
        out[1] = se / (float)B_;
    }
}

template <int NCCH>
static void run_pipeline(const float* x, const float* y, float2* part,
                         unsigned* keys, float* stats, float* out,
                         hipStream_t stream) {
    nn_partial_kernel<NCCH><<<dim3(NCCH, 2, 8), 256, 0, stream>>>(x, y, part);
    merge_keys_kernel<NCCH><<<dim3(N_ / 256, 8), 256, 0, stream>>>(x, y, part, keys);
    tail_kernel<<<8, TPB_TAIL, 0, stream>>>(keys, stats);
    final_kernel<<<1, 64, 0, stream>>>(stats, out);
}

extern "C" void kernel_launch(void* const* d_in, const int* in_sizes, int n_in,
                              void* d_out, int out_size, void* d_ws, size_t ws_size,
                              hipStream_t stream) {
    const float* x = (const float*)d_in[0];
    const float* y = (const float*)d_in[1];
    float* out = (float*)d_out;

    // Workspace: [keys 384KB][stats 64B][part ...]
    unsigned* keys  = (unsigned*)d_ws;
    float*    stats = (float*)(keys + (size_t)8 * NV);
    float2*   part  = (float2*)(stats + 16);

    const size_t head   = ((size_t)8 * NV + 16) * sizeof(float);
    const size_t need32 = head + (size_t)8 * 32 * N_ * sizeof(float2);  // ~8.8 MB

    if (ws_size >= need32) {
        run_pipeline<32>(x, y, part, keys, stats, out, stream);
    } else {
        run_pipeline<8>(x, y, part, keys, stats, out, stream);
    }
}